// Round 9
// baseline (249.859 us; speedup 1.0000x reference)
//
#include <hip/hip_runtime.h>
#include <hip/hip_fp16.h>
#include <math.h>
#include <stdint.h>

static constexpr int kN     = 50000;
static constexpr int kFIn   = 128;
static constexpr int kHeads = 4;
static constexpr int kScanB = 256;
static constexpr int kScanNB = (kN + kScanB - 1) / kScanB;   // 196

__device__ __forceinline__ float lrelu(float x) { return x > 0.f ? x : 0.2f * x; }

// ---- init: zero deg + cnt (contiguous) ----
__global__ void k_init(int* __restrict__ p, int n) {
    int i = blockIdx.x * blockDim.x + threadIdx.x;
    if (i < n) p[i] = 0;
}

// ---- layer 1 node transform: h1 = x@W1 (fp16 out), attention logits fused.
// W1 staged in LDS as FP32 (64 KB), granule-rotated: chunk c (4 floats = 16B) of
// channel j lives at granule j*32 + ((c+j)&31) -> conflict-free ds_read_b128
// (verified: SQ_LDS_BANK_CONFLICT = 0, VGPR 116, no scratch in R8).
// R8 lesson: at 256 thr/block the kernel was latency-bound (Occ 17%, VALUBusy 32%)
// -- 2 waves/SIMD can't hide the cold broadcast x-loads. This round: 512-thr
// blocks, same 64KB tile -> 2 blocks/CU (128/160 KB), 4 waves/SIMD (VGPR-capped).
__global__ __launch_bounds__(512)
void k_gemm1(const float* __restrict__ x, const float* __restrict__ W1,
             const float* __restrict__ a_src1, const float* __restrict__ a_dst1,
             __half* __restrict__ h1h, float* __restrict__ asrc, float* __restrict__ adst,
             int nPass, int grid) {
    __shared__ __align__(16) float wh[128 * 32 * 4];   // 16384 floats = 64 KB
    const int t = threadIdx.x;
    const int j = t & 63;                            // lane
    const int g = t >> 6;                            // wave 0..7
    // stage: 4096 granules; idx -> (c = idx>>7 in 0..31, col = idx&127)
    for (int idx = t; idx < 4096; idx += 512) {
        const int c = idx >> 7, col = idx & 127;
        float4 st;
        st.x = W1[(4 * c + 0) * 128 + col];          // consecutive col -> coalesced
        st.y = W1[(4 * c + 1) * 128 + col];
        st.z = W1[(4 * c + 2) * 128 + col];
        st.w = W1[(4 * c + 3) * 128 + col];
        const int gran = col * 32 + ((c + col) & 31);
        *reinterpret_cast<float4*>(&wh[gran * 4]) = st;
    }
    const float as0 = a_src1[j], as1 = a_src1[j + 64];
    const float ad0 = a_dst1[j], ad1 = a_dst1[j + 64];
    __syncthreads();

    for (int pass = blockIdx.x; pass < nPass; pass += grid) {
        const int base = pass * 64 + g * 8;          // 8 nodes for this wave
        float acc[2][8] = {};
#pragma unroll 8
        for (int c = 0; c < 32; ++c) {
            const int rot = (c + j) & 31;            // ch j+64: (c+j+64)&31 == (c+j)&31
            const float4 w0 = *(const float4*)&wh[(j * 32 + rot) * 4];
            const float4 w1v = *(const float4*)&wh[((j + 64) * 32 + rot) * 4];
#pragma unroll
            for (int nn = 0; nn < 8; ++nn) {
                int n = base + nn; if (n >= kN) n = kN - 1;          // clamp (guarded stores)
                const float4 xv = *(const float4*)&x[(size_t)n * 128 + 4 * c]; // wave-broadcast
                acc[0][nn] += w0.x * xv.x + w0.y * xv.y + w0.z * xv.z + w0.w * xv.w;
                acc[1][nn] += w1v.x * xv.x + w1v.y * xv.y + w1v.z * xv.z + w1v.w * xv.w;
            }
        }
#pragma unroll
        for (int nn = 0; nn < 8; ++nn) {
            const int n = base + nn;
            const bool valid = (n < kN);
            if (valid) {
                h1h[(size_t)n * 128 + j]      = __float2half(acc[0][nn]);
                h1h[(size_t)n * 128 + 64 + j] = __float2half(acc[1][nn]);
            }
            float ps0 = acc[0][nn] * as0, ps1 = acc[1][nn] * as1;
            float pd0 = acc[0][nn] * ad0, pd1 = acc[1][nn] * ad1;
#pragma unroll
            for (int off = 16; off >= 1; off >>= 1) {   // reduce within 32-lane halves
                ps0 += __shfl_xor(ps0, off, 64);
                ps1 += __shfl_xor(ps1, off, 64);
                pd0 += __shfl_xor(pd0, off, 64);
                pd1 += __shfl_xor(pd1, off, 64);
            }
            if (valid && ((j & 31) == 0)) {
                const int h01 = j >> 5;                 // lanes 0..31 -> heads {0,2}; 32..63 -> {1,3}
                asrc[n * 4 + h01]     = ps0;
                asrc[n * 4 + 2 + h01] = ps1;
                adst[n * 4 + h01]     = pd0;
                adst[n * 4 + 2 + h01] = pd1;
            }
        }
    }
}

// ---- CSR build ----
__global__ void k_hist(const int* __restrict__ ei, int E, int* __restrict__ deg) {
    int i = blockIdx.x * blockDim.x + threadIdx.x;
    int total = E + kN;
    if (i >= total) return;
    int d = (i < E) ? ei[E + i] : (i - E);
    atomicAdd(&deg[d], 1);
}

__global__ void k_scan_a(const int* __restrict__ deg, int* __restrict__ loc, int* __restrict__ bsum) {
    __shared__ int tmp[kScanB];
    int t = threadIdx.x;
    int i = blockIdx.x * kScanB + t;
    int v = (i < kN) ? deg[i] : 0;
    tmp[t] = v;
    __syncthreads();
    for (int off = 1; off < kScanB; off <<= 1) {
        int add = (t >= off) ? tmp[t - off] : 0;
        __syncthreads();
        tmp[t] += add;
        __syncthreads();
    }
    if (i < kN) loc[i] = tmp[t] - v;     // exclusive within block
    if (t == kScanB - 1) bsum[blockIdx.x] = tmp[t];
}

// parallel exclusive scan of the 196 block sums (one 256-thread block)
__global__ void k_scan_b(int* __restrict__ bsum) {
    __shared__ int tmp[256];
    int t = threadIdx.x;
    int v = (t < kScanNB) ? bsum[t] : 0;
    tmp[t] = v;
    __syncthreads();
    for (int off = 1; off < 256; off <<= 1) {
        int add = (t >= off) ? tmp[t - off] : 0;
        __syncthreads();
        tmp[t] += add;
        __syncthreads();
    }
    if (t < kScanNB) bsum[t] = tmp[t] - v;   // exclusive
}

__global__ void k_scan_c(const int* __restrict__ loc, const int* __restrict__ bsum,
                         int* __restrict__ rowptr, int E2) {
    int i = blockIdx.x * kScanB + threadIdx.x;
    if (i < kN) rowptr[i] = loc[i] + bsum[blockIdx.x];
    if (i == 0) rowptr[kN] = E2;
}

// ---- scatter: bucket edge sources by dst (es only; weights recomputed in agg1) ----
__global__ void k_scatter(const int* __restrict__ ei, int E,
                          const int* __restrict__ rowptr, int* __restrict__ cnt,
                          int* __restrict__ es) {
    int i = blockIdx.x * blockDim.x + threadIdx.x;
    int total = E + kN;
    if (i >= total) return;
    int s, d;
    if (i < E) { s = ei[i]; d = ei[E + i]; } else { s = d = i - E; }
    int pos = rowptr[d] + atomicAdd(&cnt[d], 1);
    es[pos] = s;
}

// ---- layer 1 aggregation: 1 wave per node, lane = 2 channels (half2 gather),
//      softmax weights recomputed from L2-resident asrc/adst; epilogue in-register:
//      head-mean + bias + ELU + layer-2 matvec -> h2[n]. No LDS, no atomics.
__global__ __launch_bounds__(256)
void k_agg1(const int* __restrict__ rowptr, const int* __restrict__ es,
            const float* __restrict__ asrc, const float* __restrict__ adst,
            const __half* __restrict__ h1h, const float* __restrict__ b1,
            const float* __restrict__ W2, float* __restrict__ h2) {
    const int n = blockIdx.x * 4 + (threadIdx.x >> 6);
    if (n >= kN) return;
    const int j  = threadIdx.x & 63;     // lane: channels 2j, 2j+1
    const int hh = j >> 4;               // head of both channels
    const float adv = adst[n * 4 + hh];
    const int beg = rowptr[n], end = rowptr[n + 1];
    float ax0 = 0.f, ay0 = 0.f, dn0 = 0.f;
    float ax1 = 0.f, ay1 = 0.f, dn1 = 0.f;
    int p = beg;
    for (; p + 2 <= end; p += 2) {
        const int s0 = es[p], s1 = es[p + 1];
        const float e0 = asrc[s0 * 4 + hh] + adv;
        const float e1 = asrc[s1 * 4 + hh] + adv;
        const __half2 v0 = *(const __half2*)&h1h[(size_t)s0 * 128 + 2 * j];  // global: ok
        const __half2 v1 = *(const __half2*)&h1h[(size_t)s1 * 128 + 2 * j];
        const float w0 = expf(lrelu(e0));
        const float w1 = expf(lrelu(e1));
        const float2 f0 = __half22float2(v0);
        const float2 f1 = __half22float2(v1);
        ax0 += w0 * f0.x; ay0 += w0 * f0.y; dn0 += w0;
        ax1 += w1 * f1.x; ay1 += w1 * f1.y; dn1 += w1;
    }
    if (p < end) {
        const int s0 = es[p];
        const float e0 = asrc[s0 * 4 + hh] + adv;
        const __half2 v0 = *(const __half2*)&h1h[(size_t)s0 * 128 + 2 * j];
        const float w0 = expf(lrelu(e0));
        const float2 f0 = __half22float2(v0);
        ax0 += w0 * f0.x; ay0 += w0 * f0.y; dn0 += w0;
    }
    const float den = dn0 + dn1;
    float vx = (ax0 + ax1) / den;
    float vy = (ay0 + ay1) / den;
    // mean over heads: lanes {j, j^16, j^32, j^48} hold the 4 heads of channel pair (j&15)
    vx += __shfl_xor(vx, 32, 64); vy += __shfl_xor(vy, 32, 64);
    vx += __shfl_xor(vx, 16, 64); vy += __shfl_xor(vy, 16, 64);
    const int m = j & 15;                // channel pair (2m, 2m+1)
    float u0 = 0.25f * vx + b1[2 * m];
    float u1 = 0.25f * vy + b1[2 * m + 1];
    u0 = u0 > 0.f ? u0 : expf(u0) - 1.f;
    u1 = u1 > 0.f ? u1 : expf(u1) - 1.f;
    float tsum = u0 * W2[2 * m] + u1 * W2[2 * m + 1];
    tsum += __shfl_xor(tsum, 8, 64);
    tsum += __shfl_xor(tsum, 4, 64);
    tsum += __shfl_xor(tsum, 2, 64);
    tsum += __shfl_xor(tsum, 1, 64);
    if (j == 0) h2[n] = tsum;
}

// ---- layer 2: 16 lanes per node, gather h2 (L2-resident), fused bias -> out ----
__global__ __launch_bounds__(256)
void k_agg2(const int* __restrict__ rowptr, const int* __restrict__ es,
            const float* __restrict__ h2,
            const float* __restrict__ a_s2, const float* __restrict__ a_d2,
            const float* __restrict__ b2, float* __restrict__ out) {
    const int n = blockIdx.x * 16 + (threadIdx.x >> 4);
    if (n >= kN) return;
    const int l = threadIdx.x & 15;
    const float as = a_s2[0], ad = a_d2[0];
    const int beg = rowptr[n], end = rowptr[n + 1];
    const float hd = h2[n] * ad;
    float sw = 0.f, swh = 0.f;
    for (int p = beg + l; p < end; p += 16) {
        float hs = h2[es[p]];
        float w = expf(lrelu(hs * as + hd));
        sw += w;
        swh += w * hs;
    }
#pragma unroll
    for (int off = 8; off >= 1; off >>= 1) {
        sw  += __shfl_xor(sw, off, 64);
        swh += __shfl_xor(swh, off, 64);
    }
    if (l == 0) out[n] = swh / sw + b2[0];
}

extern "C" void kernel_launch(void* const* d_in, const int* in_sizes, int n_in,
                              void* d_out, int out_size, void* d_ws, size_t ws_size,
                              hipStream_t stream) {
    const float* x      = (const float*)d_in[0];
    const int*   ei     = (const int*)d_in[1];
    const float* W1     = (const float*)d_in[3];
    const float* a_src1 = (const float*)d_in[4];
    const float* a_dst1 = (const float*)d_in[5];
    const float* b1     = (const float*)d_in[6];
    const float* W2     = (const float*)d_in[7];
    const float* a_src2 = (const float*)d_in[8];
    const float* a_dst2 = (const float*)d_in[9];
    const float* b2     = (const float*)d_in[10];
    float* out = (float*)d_out;

    const int E  = in_sizes[1] / 2;      // 800000
    const int E2 = E + kN;               // 850000

    // workspace layout (float offsets)
    float*  ws    = (float*)d_ws;
    float*  asrc  = ws;                          //   200,000 f
    float*  adst  = ws + 200000;                 //   200,000 f
    float*  h2    = ws + 400000;                 //    50,000 f
    __half* h1h   = (__half*)(ws + 450000);      // 6,400,000 h = 3,200,000 f
    int*    ibase = (int*)(ws + 3650000);
    int*    es     = ibase;                      //   850,000 i
    int*    deg    = ibase + 850000;             //    50,000 i
    int*    cnt    = ibase + 900000;             //    50,000 i
    int*    loc    = ibase + 950000;             //    50,000 i
    int*    rowptr = ibase + 1000000;            //    50,001 i
    int*    bsum   = ibase + 1050016;            //       256 i

    k_init<<<(100000 + 255) / 256, 256, 0, stream>>>(deg, 100000);  // deg+cnt contiguous

    k_hist<<<(E2 + 255) / 256, 256, 0, stream>>>(ei, E, deg);
    k_scan_a<<<kScanNB, kScanB, 0, stream>>>(deg, loc, bsum);
    k_scan_b<<<1, 256, 0, stream>>>(bsum);
    k_scan_c<<<kScanNB, kScanB, 0, stream>>>(loc, bsum, rowptr, E2);

    {
        const int nPass = (kN + 63) / 64;        // 782 (64 nodes per block-pass)
        k_gemm1<<<512, 512, 0, stream>>>(x, W1, a_src1, a_dst1, h1h, asrc, adst, nPass, 512);
    }

    k_scatter<<<(E2 + 255) / 256, 256, 0, stream>>>(ei, E, rowptr, cnt, es);

    k_agg1<<<(kN + 3) / 4, 256, 0, stream>>>(rowptr, es, asrc, adst, h1h, b1, W2, h2);

    k_agg2<<<(kN + 15) / 16, 256, 0, stream>>>(rowptr, es, h2, a_src2, a_dst2, b2, out);
}

// Round 10
// 222.936 us; speedup vs baseline: 1.1208x; 1.1208x over previous
//
#include <hip/hip_runtime.h>
#include <hip/hip_fp16.h>
#include <math.h>
#include <stdint.h>

static constexpr int kN     = 50000;
static constexpr int kFIn   = 128;
static constexpr int kHeads = 4;
static constexpr int kScanB = 256;
static constexpr int kScanNB = (kN + kScanB - 1) / kScanB;   // 196

__device__ __forceinline__ float lrelu(float x) { return x > 0.f ? x : 0.2f * x; }

// ---- init: zero deg + cnt (contiguous) ----
__global__ void k_init(int* __restrict__ p, int n) {
    int i = blockIdx.x * blockDim.x + threadIdx.x;
    if (i < n) p[i] = 0;
}

// ---- layer 1 node transform: h1 = x@W1 (fp16 out), attention logits fused.
// W1 staged in LDS as FP32 (64 KB), granule-rotated (verified conflict-free, clean
// codegen: VGPR 116, FETCH 13 MB). R9 lesson: the bottleneck was 256 per-wave
// BROADCAST global x-loads per pass (~400+ cyc L3 latency, ~10 in flight) -- block
// size didn't matter. R10: stage the 32-node x-tile in LDS per pass via coalesced
// per-lane float4 loads (one burst), inner loop reads x via LDS broadcast (free).
// LDS = 64 + 16 = 80 KB -> 2 blocks/CU.
__global__ __launch_bounds__(256)
void k_gemm1(const float* __restrict__ x, const float* __restrict__ W1,
             const float* __restrict__ a_src1, const float* __restrict__ a_dst1,
             __half* __restrict__ h1h, float* __restrict__ asrc, float* __restrict__ adst,
             int nPass, int grid) {
    __shared__ __align__(16) float wh[128 * 32 * 4];   // 16384 floats = 64 KB (W1, rotated)
    __shared__ __align__(16) float xs[32 * 128];       //  4096 floats = 16 KB (x tile)
    const int t = threadIdx.x;
    const int j = t & 63;                            // lane
    const int g = t >> 6;                            // wave 0..3
    // stage W1: 4096 granules; idx -> (c = idx>>7 in 0..31, col = idx&127)
    for (int idx = t; idx < 4096; idx += 256) {
        const int c = idx >> 7, col = idx & 127;
        float4 st;
        st.x = W1[(4 * c + 0) * 128 + col];          // consecutive col -> coalesced
        st.y = W1[(4 * c + 1) * 128 + col];
        st.z = W1[(4 * c + 2) * 128 + col];
        st.w = W1[(4 * c + 3) * 128 + col];
        const int gran = col * 32 + ((c + col) & 31);
        *reinterpret_cast<float4*>(&wh[gran * 4]) = st;
    }
    const float as0 = a_src1[j], as1 = a_src1[j + 64];
    const float ad0 = a_dst1[j], ad1 = a_dst1[j + 64];
    __syncthreads();

    for (int pass = blockIdx.x; pass < nPass; pass += grid) {
        const int nodeBase = pass * 32;
        // stage 32 nodes of x: 1024 float4s, 4 per thread, coalesced
        for (int q = t; q < 1024; q += 256) {
            const int nn = q >> 5;                   // node 0..31
            const int ck = q & 31;                   // float4 chunk 0..31
            int n = nodeBase + nn; if (n >= kN) n = kN - 1;
            *reinterpret_cast<float4*>(&xs[q * 4]) =
                *reinterpret_cast<const float4*>(&x[(size_t)n * 128 + ck * 4]);
        }
        __syncthreads();

        const int base = g * 8;                      // this wave's 8 local nodes
        float acc[2][8] = {};
#pragma unroll 8
        for (int c = 0; c < 32; ++c) {
            const int rot = (c + j) & 31;            // ch j+64: (c+j+64)&31 == (c+j)&31
            const float4 w0 = *(const float4*)&wh[(j * 32 + rot) * 4];
            const float4 w1v = *(const float4*)&wh[((j + 64) * 32 + rot) * 4];
#pragma unroll
            for (int nn = 0; nn < 8; ++nn) {
                const float4 xv = *(const float4*)&xs[((base + nn) * 32 + c) * 4]; // LDS broadcast
                acc[0][nn] += w0.x * xv.x + w0.y * xv.y + w0.z * xv.z + w0.w * xv.w;
                acc[1][nn] += w1v.x * xv.x + w1v.y * xv.y + w1v.z * xv.z + w1v.w * xv.w;
            }
        }
#pragma unroll
        for (int nn = 0; nn < 8; ++nn) {
            const int n = nodeBase + base + nn;
            const bool valid = (n < kN);
            if (valid) {
                h1h[(size_t)n * 128 + j]      = __float2half(acc[0][nn]);
                h1h[(size_t)n * 128 + 64 + j] = __float2half(acc[1][nn]);
            }
            float ps0 = acc[0][nn] * as0, ps1 = acc[1][nn] * as1;
            float pd0 = acc[0][nn] * ad0, pd1 = acc[1][nn] * ad1;
#pragma unroll
            for (int off = 16; off >= 1; off >>= 1) {   // reduce within 32-lane halves
                ps0 += __shfl_xor(ps0, off, 64);
                ps1 += __shfl_xor(ps1, off, 64);
                pd0 += __shfl_xor(pd0, off, 64);
                pd1 += __shfl_xor(pd1, off, 64);
            }
            if (valid && ((j & 31) == 0)) {
                const int h01 = j >> 5;                 // lanes 0..31 -> heads {0,2}; 32..63 -> {1,3}
                asrc[n * 4 + h01]     = ps0;
                asrc[n * 4 + 2 + h01] = ps1;
                adst[n * 4 + h01]     = pd0;
                adst[n * 4 + 2 + h01] = pd1;
            }
        }
        __syncthreads();                             // protect xs before next stage
    }
}

// ---- CSR build ----
__global__ void k_hist(const int* __restrict__ ei, int E, int* __restrict__ deg) {
    int i = blockIdx.x * blockDim.x + threadIdx.x;
    int total = E + kN;
    if (i >= total) return;
    int d = (i < E) ? ei[E + i] : (i - E);
    atomicAdd(&deg[d], 1);
}

__global__ void k_scan_a(const int* __restrict__ deg, int* __restrict__ loc, int* __restrict__ bsum) {
    __shared__ int tmp[kScanB];
    int t = threadIdx.x;
    int i = blockIdx.x * kScanB + t;
    int v = (i < kN) ? deg[i] : 0;
    tmp[t] = v;
    __syncthreads();
    for (int off = 1; off < kScanB; off <<= 1) {
        int add = (t >= off) ? tmp[t - off] : 0;
        __syncthreads();
        tmp[t] += add;
        __syncthreads();
    }
    if (i < kN) loc[i] = tmp[t] - v;     // exclusive within block
    if (t == kScanB - 1) bsum[blockIdx.x] = tmp[t];
}

// parallel exclusive scan of the 196 block sums (one 256-thread block)
__global__ void k_scan_b(int* __restrict__ bsum) {
    __shared__ int tmp[256];
    int t = threadIdx.x;
    int v = (t < kScanNB) ? bsum[t] : 0;
    tmp[t] = v;
    __syncthreads();
    for (int off = 1; off < 256; off <<= 1) {
        int add = (t >= off) ? tmp[t - off] : 0;
        __syncthreads();
        tmp[t] += add;
        __syncthreads();
    }
    if (t < kScanNB) bsum[t] = tmp[t] - v;   // exclusive
}

__global__ void k_scan_c(const int* __restrict__ loc, const int* __restrict__ bsum,
                         int* __restrict__ rowptr, int E2) {
    int i = blockIdx.x * kScanB + threadIdx.x;
    if (i < kN) rowptr[i] = loc[i] + bsum[blockIdx.x];
    if (i == 0) rowptr[kN] = E2;
}

// ---- scatter: bucket edge sources by dst (es only; weights recomputed in agg1) ----
__global__ void k_scatter(const int* __restrict__ ei, int E,
                          const int* __restrict__ rowptr, int* __restrict__ cnt,
                          int* __restrict__ es) {
    int i = blockIdx.x * blockDim.x + threadIdx.x;
    int total = E + kN;
    if (i >= total) return;
    int s, d;
    if (i < E) { s = ei[i]; d = ei[E + i]; } else { s = d = i - E; }
    int pos = rowptr[d] + atomicAdd(&cnt[d], 1);
    es[pos] = s;
}

// ---- layer 1 aggregation: 1 wave per node, lane = 2 channels (half2 gather),
//      softmax weights recomputed from L2-resident asrc/adst; epilogue in-register:
//      head-mean + bias + ELU + layer-2 matvec -> h2[n]. No LDS, no atomics.
__global__ __launch_bounds__(256)
void k_agg1(const int* __restrict__ rowptr, const int* __restrict__ es,
            const float* __restrict__ asrc, const float* __restrict__ adst,
            const __half* __restrict__ h1h, const float* __restrict__ b1,
            const float* __restrict__ W2, float* __restrict__ h2) {
    const int n = blockIdx.x * 4 + (threadIdx.x >> 6);
    if (n >= kN) return;
    const int j  = threadIdx.x & 63;     // lane: channels 2j, 2j+1
    const int hh = j >> 4;               // head of both channels
    const float adv = adst[n * 4 + hh];
    const int beg = rowptr[n], end = rowptr[n + 1];
    float ax0 = 0.f, ay0 = 0.f, dn0 = 0.f;
    float ax1 = 0.f, ay1 = 0.f, dn1 = 0.f;
    int p = beg;
    for (; p + 2 <= end; p += 2) {
        const int s0 = es[p], s1 = es[p + 1];
        const float e0 = asrc[s0 * 4 + hh] + adv;
        const float e1 = asrc[s1 * 4 + hh] + adv;
        const __half2 v0 = *(const __half2*)&h1h[(size_t)s0 * 128 + 2 * j];  // global: ok
        const __half2 v1 = *(const __half2*)&h1h[(size_t)s1 * 128 + 2 * j];
        const float w0 = expf(lrelu(e0));
        const float w1 = expf(lrelu(e1));
        const float2 f0 = __half22float2(v0);
        const float2 f1 = __half22float2(v1);
        ax0 += w0 * f0.x; ay0 += w0 * f0.y; dn0 += w0;
        ax1 += w1 * f1.x; ay1 += w1 * f1.y; dn1 += w1;
    }
    if (p < end) {
        const int s0 = es[p];
        const float e0 = asrc[s0 * 4 + hh] + adv;
        const __half2 v0 = *(const __half2*)&h1h[(size_t)s0 * 128 + 2 * j];
        const float w0 = expf(lrelu(e0));
        const float2 f0 = __half22float2(v0);
        ax0 += w0 * f0.x; ay0 += w0 * f0.y; dn0 += w0;
    }
    const float den = dn0 + dn1;
    float vx = (ax0 + ax1) / den;
    float vy = (ay0 + ay1) / den;
    // mean over heads: lanes {j, j^16, j^32, j^48} hold the 4 heads of channel pair (j&15)
    vx += __shfl_xor(vx, 32, 64); vy += __shfl_xor(vy, 32, 64);
    vx += __shfl_xor(vx, 16, 64); vy += __shfl_xor(vy, 16, 64);
    const int m = j & 15;                // channel pair (2m, 2m+1)
    float u0 = 0.25f * vx + b1[2 * m];
    float u1 = 0.25f * vy + b1[2 * m + 1];
    u0 = u0 > 0.f ? u0 : expf(u0) - 1.f;
    u1 = u1 > 0.f ? u1 : expf(u1) - 1.f;
    float tsum = u0 * W2[2 * m] + u1 * W2[2 * m + 1];
    tsum += __shfl_xor(tsum, 8, 64);
    tsum += __shfl_xor(tsum, 4, 64);
    tsum += __shfl_xor(tsum, 2, 64);
    tsum += __shfl_xor(tsum, 1, 64);
    if (j == 0) h2[n] = tsum;
}

// ---- layer 2: 16 lanes per node, gather h2 (L2-resident), fused bias -> out ----
__global__ __launch_bounds__(256)
void k_agg2(const int* __restrict__ rowptr, const int* __restrict__ es,
            const float* __restrict__ h2,
            const float* __restrict__ a_s2, const float* __restrict__ a_d2,
            const float* __restrict__ b2, float* __restrict__ out) {
    const int n = blockIdx.x * 16 + (threadIdx.x >> 4);
    if (n >= kN) return;
    const int l = threadIdx.x & 15;
    const float as = a_s2[0], ad = a_d2[0];
    const int beg = rowptr[n], end = rowptr[n + 1];
    const float hd = h2[n] * ad;
    float sw = 0.f, swh = 0.f;
    for (int p = beg + l; p < end; p += 16) {
        float hs = h2[es[p]];
        float w = expf(lrelu(hs * as + hd));
        sw += w;
        swh += w * hs;
    }
#pragma unroll
    for (int off = 8; off >= 1; off >>= 1) {
        sw  += __shfl_xor(sw, off, 64);
        swh += __shfl_xor(swh, off, 64);
    }
    if (l == 0) out[n] = swh / sw + b2[0];
}

extern "C" void kernel_launch(void* const* d_in, const int* in_sizes, int n_in,
                              void* d_out, int out_size, void* d_ws, size_t ws_size,
                              hipStream_t stream) {
    const float* x      = (const float*)d_in[0];
    const int*   ei     = (const int*)d_in[1];
    const float* W1     = (const float*)d_in[3];
    const float* a_src1 = (const float*)d_in[4];
    const float* a_dst1 = (const float*)d_in[5];
    const float* b1     = (const float*)d_in[6];
    const float* W2     = (const float*)d_in[7];
    const float* a_src2 = (const float*)d_in[8];
    const float* a_dst2 = (const float*)d_in[9];
    const float* b2     = (const float*)d_in[10];
    float* out = (float*)d_out;

    const int E  = in_sizes[1] / 2;      // 800000
    const int E2 = E + kN;               // 850000

    // workspace layout (float offsets)
    float*  ws    = (float*)d_ws;
    float*  asrc  = ws;                          //   200,000 f
    float*  adst  = ws + 200000;                 //   200,000 f
    float*  h2    = ws + 400000;                 //    50,000 f
    __half* h1h   = (__half*)(ws + 450000);      // 6,400,000 h = 3,200,000 f
    int*    ibase = (int*)(ws + 3650000);
    int*    es     = ibase;                      //   850,000 i
    int*    deg    = ibase + 850000;             //    50,000 i
    int*    cnt    = ibase + 900000;             //    50,000 i
    int*    loc    = ibase + 950000;             //    50,000 i
    int*    rowptr = ibase + 1000000;            //    50,001 i
    int*    bsum   = ibase + 1050016;            //       256 i

    k_init<<<(100000 + 255) / 256, 256, 0, stream>>>(deg, 100000);  // deg+cnt contiguous

    k_hist<<<(E2 + 255) / 256, 256, 0, stream>>>(ei, E, deg);
    k_scan_a<<<kScanNB, kScanB, 0, stream>>>(deg, loc, bsum);
    k_scan_b<<<1, 256, 0, stream>>>(bsum);
    k_scan_c<<<kScanNB, kScanB, 0, stream>>>(loc, bsum, rowptr, E2);

    {
        const int nPass = (kN + 31) / 32;        // 1563
        k_gemm1<<<512, 256, 0, stream>>>(x, W1, a_src1, a_dst1, h1h, asrc, adst, nPass, 512);
    }

    k_scatter<<<(E2 + 255) / 256, 256, 0, stream>>>(ei, E, rowptr, cnt, es);

    k_agg1<<<(kN + 3) / 4, 256, 0, stream>>>(rowptr, es, asrc, adst, h1h, b1, W2, h2);

    k_agg2<<<(kN + 15) / 16, 256, 0, stream>>>(rowptr, es, h2, a_src2, a_dst2, b2, out);
}

// Round 11
// 202.718 us; speedup vs baseline: 1.2325x; 1.0997x over previous
//
#include <hip/hip_runtime.h>
#include <hip/hip_fp16.h>
#include <math.h>
#include <stdint.h>

static constexpr int kN     = 50000;
static constexpr int kFIn   = 128;
static constexpr int kHeads = 4;
static constexpr int kScanB = 256;
static constexpr int kScanNB = (kN + kScanB - 1) / kScanB;   // 196

__device__ __forceinline__ float lrelu(float x) { return x > 0.f ? x : 0.2f * x; }

// ---- init: zero deg + cnt (contiguous) ----
__global__ void k_init(int* __restrict__ p, int n) {
    int i = blockIdx.x * blockDim.x + threadIdx.x;
    if (i < n) p[i] = 0;
}

// ---- layer 1 node transform: h1 = x@W1 (fp16 out), attention logits fused.
// W1 in LDS fp32 (64 KB, granule-rotated, conflict-free); x tile (32 nodes, 16 KB)
// staged per pass via coalesced float4 loads, read back as LDS broadcast.
// (R10 verified: gemm1 dropped out of top-5.)
__global__ __launch_bounds__(256)
void k_gemm1(const float* __restrict__ x, const float* __restrict__ W1,
             const float* __restrict__ a_src1, const float* __restrict__ a_dst1,
             __half* __restrict__ h1h, float* __restrict__ asrc, float* __restrict__ adst,
             int nPass, int grid) {
    __shared__ __align__(16) float wh[128 * 32 * 4];   // 64 KB (W1, rotated)
    __shared__ __align__(16) float xs[32 * 128];       // 16 KB (x tile)
    const int t = threadIdx.x;
    const int j = t & 63;                            // lane
    const int g = t >> 6;                            // wave 0..3
    for (int idx = t; idx < 4096; idx += 256) {
        const int c = idx >> 7, col = idx & 127;
        float4 st;
        st.x = W1[(4 * c + 0) * 128 + col];
        st.y = W1[(4 * c + 1) * 128 + col];
        st.z = W1[(4 * c + 2) * 128 + col];
        st.w = W1[(4 * c + 3) * 128 + col];
        const int gran = col * 32 + ((c + col) & 31);
        *reinterpret_cast<float4*>(&wh[gran * 4]) = st;
    }
    const float as0 = a_src1[j], as1 = a_src1[j + 64];
    const float ad0 = a_dst1[j], ad1 = a_dst1[j + 64];
    __syncthreads();

    for (int pass = blockIdx.x; pass < nPass; pass += grid) {
        const int nodeBase = pass * 32;
        for (int q = t; q < 1024; q += 256) {
            const int nn = q >> 5;
            const int ck = q & 31;
            int n = nodeBase + nn; if (n >= kN) n = kN - 1;
            *reinterpret_cast<float4*>(&xs[q * 4]) =
                *reinterpret_cast<const float4*>(&x[(size_t)n * 128 + ck * 4]);
        }
        __syncthreads();

        const int base = g * 8;
        float acc[2][8] = {};
#pragma unroll 8
        for (int c = 0; c < 32; ++c) {
            const int rot = (c + j) & 31;
            const float4 w0 = *(const float4*)&wh[(j * 32 + rot) * 4];
            const float4 w1v = *(const float4*)&wh[((j + 64) * 32 + rot) * 4];
#pragma unroll
            for (int nn = 0; nn < 8; ++nn) {
                const float4 xv = *(const float4*)&xs[((base + nn) * 32 + c) * 4];
                acc[0][nn] += w0.x * xv.x + w0.y * xv.y + w0.z * xv.z + w0.w * xv.w;
                acc[1][nn] += w1v.x * xv.x + w1v.y * xv.y + w1v.z * xv.z + w1v.w * xv.w;
            }
        }
#pragma unroll
        for (int nn = 0; nn < 8; ++nn) {
            const int n = nodeBase + base + nn;
            const bool valid = (n < kN);
            if (valid) {
                h1h[(size_t)n * 128 + j]      = __float2half(acc[0][nn]);
                h1h[(size_t)n * 128 + 64 + j] = __float2half(acc[1][nn]);
            }
            float ps0 = acc[0][nn] * as0, ps1 = acc[1][nn] * as1;
            float pd0 = acc[0][nn] * ad0, pd1 = acc[1][nn] * ad1;
#pragma unroll
            for (int off = 16; off >= 1; off >>= 1) {
                ps0 += __shfl_xor(ps0, off, 64);
                ps1 += __shfl_xor(ps1, off, 64);
                pd0 += __shfl_xor(pd0, off, 64);
                pd1 += __shfl_xor(pd1, off, 64);
            }
            if (valid && ((j & 31) == 0)) {
                const int h01 = j >> 5;
                asrc[n * 4 + h01]     = ps0;
                asrc[n * 4 + 2 + h01] = ps1;
                adst[n * 4 + h01]     = pd0;
                adst[n * 4 + 2 + h01] = pd1;
            }
        }
        __syncthreads();
    }
}

// ---- CSR build ----
__global__ void k_hist(const int* __restrict__ ei, int E, int* __restrict__ deg) {
    int i = blockIdx.x * blockDim.x + threadIdx.x;
    int total = E + kN;
    if (i >= total) return;
    int d = (i < E) ? ei[E + i] : (i - E);
    atomicAdd(&deg[d], 1);
}

__global__ void k_scan_a(const int* __restrict__ deg, int* __restrict__ loc, int* __restrict__ bsum) {
    __shared__ int tmp[kScanB];
    int t = threadIdx.x;
    int i = blockIdx.x * kScanB + t;
    int v = (i < kN) ? deg[i] : 0;
    tmp[t] = v;
    __syncthreads();
    for (int off = 1; off < kScanB; off <<= 1) {
        int add = (t >= off) ? tmp[t - off] : 0;
        __syncthreads();
        tmp[t] += add;
        __syncthreads();
    }
    if (i < kN) loc[i] = tmp[t] - v;     // exclusive within block
    if (t == kScanB - 1) bsum[blockIdx.x] = tmp[t];
}

__global__ void k_scan_b(int* __restrict__ bsum) {
    __shared__ int tmp[256];
    int t = threadIdx.x;
    int v = (t < kScanNB) ? bsum[t] : 0;
    tmp[t] = v;
    __syncthreads();
    for (int off = 1; off < 256; off <<= 1) {
        int add = (t >= off) ? tmp[t - off] : 0;
        __syncthreads();
        tmp[t] += add;
        __syncthreads();
    }
    if (t < kScanNB) bsum[t] = tmp[t] - v;   // exclusive
}

__global__ void k_scan_c(const int* __restrict__ loc, const int* __restrict__ bsum,
                         int* __restrict__ rowptr, int E2) {
    int i = blockIdx.x * kScanB + threadIdx.x;
    if (i < kN) rowptr[i] = loc[i] + bsum[blockIdx.x];
    if (i == 0) rowptr[kN] = E2;
}

// ---- scatter: bucket edges by dst AND precompute the 4 per-edge softmax weights
//      (one expf per head per edge, instead of 16-lane-redundant expf in agg1 --
//      R10 showed agg1 at VALUBusy 80%, dominated by redundant weight recompute).
__global__ void k_scatter(const int* __restrict__ ei, int E,
                          const float* __restrict__ asrc, const float* __restrict__ adst,
                          const int* __restrict__ rowptr, int* __restrict__ cnt,
                          int* __restrict__ es, float* __restrict__ wgt) {
    int i = blockIdx.x * blockDim.x + threadIdx.x;
    int total = E + kN;
    if (i >= total) return;
    int s, d;
    if (i < E) { s = ei[i]; d = ei[E + i]; } else { s = d = i - E; }
    int pos = rowptr[d] + atomicAdd(&cnt[d], 1);
    es[pos] = s;
    float4 w4;
    w4.x = expf(lrelu(asrc[s * 4 + 0] + adst[d * 4 + 0]));
    w4.y = expf(lrelu(asrc[s * 4 + 1] + adst[d * 4 + 1]));
    w4.z = expf(lrelu(asrc[s * 4 + 2] + adst[d * 4 + 2]));
    w4.w = expf(lrelu(asrc[s * 4 + 3] + adst[d * 4 + 3]));
    *reinterpret_cast<float4*>(&wgt[pos * 4]) = w4;
}

// ---- layer 1 aggregation: 1 wave per node, lane = 2 channels (half2 gather),
//      weights PRELOADED from wgt (no expf, no asrc/adst); pure gather+FMA loop,
//      4-unrolled for MLP. Epilogue: head-mean + bias + ELU + layer-2 matvec.
__global__ __launch_bounds__(256)
void k_agg1(const int* __restrict__ rowptr, const int* __restrict__ es,
            const float* __restrict__ wgt,
            const __half* __restrict__ h1h, const float* __restrict__ b1,
            const float* __restrict__ W2, float* __restrict__ h2) {
    const int n = blockIdx.x * 4 + (threadIdx.x >> 6);
    if (n >= kN) return;
    const int j  = threadIdx.x & 63;     // lane: channels 2j, 2j+1
    const int hh = j >> 4;               // head of both channels
    const int beg = rowptr[n], end = rowptr[n + 1];
    float ax0 = 0.f, ay0 = 0.f, dn0 = 0.f;
    float ax1 = 0.f, ay1 = 0.f, dn1 = 0.f;
    int p = beg;
    for (; p + 4 <= end; p += 4) {
        const int s0 = es[p],     s1 = es[p + 1];
        const int s2 = es[p + 2], s3 = es[p + 3];
        const float w0 = wgt[(p + 0) * 4 + hh];
        const float w1 = wgt[(p + 1) * 4 + hh];
        const float w2 = wgt[(p + 2) * 4 + hh];
        const float w3 = wgt[(p + 3) * 4 + hh];
        const float2 f0 = __half22float2(*(const __half2*)&h1h[s0 * 128 + 2 * j]);
        const float2 f1 = __half22float2(*(const __half2*)&h1h[s1 * 128 + 2 * j]);
        const float2 f2 = __half22float2(*(const __half2*)&h1h[s2 * 128 + 2 * j]);
        const float2 f3 = __half22float2(*(const __half2*)&h1h[s3 * 128 + 2 * j]);
        ax0 += w0 * f0.x; ay0 += w0 * f0.y; dn0 += w0;
        ax1 += w1 * f1.x; ay1 += w1 * f1.y; dn1 += w1;
        ax0 += w2 * f2.x; ay0 += w2 * f2.y; dn0 += w2;
        ax1 += w3 * f3.x; ay1 += w3 * f3.y; dn1 += w3;
    }
    for (; p < end; ++p) {
        const int s0 = es[p];
        const float w0 = wgt[p * 4 + hh];
        const float2 f0 = __half22float2(*(const __half2*)&h1h[s0 * 128 + 2 * j]);
        ax0 += w0 * f0.x; ay0 += w0 * f0.y; dn0 += w0;
    }
    const float den = dn0 + dn1;
    float vx = (ax0 + ax1) / den;
    float vy = (ay0 + ay1) / den;
    // mean over heads: lanes {j, j^16, j^32, j^48} hold the 4 heads of channel pair (j&15)
    vx += __shfl_xor(vx, 32, 64); vy += __shfl_xor(vy, 32, 64);
    vx += __shfl_xor(vx, 16, 64); vy += __shfl_xor(vy, 16, 64);
    const int m = j & 15;                // channel pair (2m, 2m+1)
    float u0 = 0.25f * vx + b1[2 * m];
    float u1 = 0.25f * vy + b1[2 * m + 1];
    u0 = u0 > 0.f ? u0 : expf(u0) - 1.f;
    u1 = u1 > 0.f ? u1 : expf(u1) - 1.f;
    float tsum = u0 * W2[2 * m] + u1 * W2[2 * m + 1];
    tsum += __shfl_xor(tsum, 8, 64);
    tsum += __shfl_xor(tsum, 4, 64);
    tsum += __shfl_xor(tsum, 2, 64);
    tsum += __shfl_xor(tsum, 1, 64);
    if (j == 0) h2[n] = tsum;
}

// ---- layer 2: 16 lanes per node, gather h2 (L2-resident), fused bias -> out ----
__global__ __launch_bounds__(256)
void k_agg2(const int* __restrict__ rowptr, const int* __restrict__ es,
            const float* __restrict__ h2,
            const float* __restrict__ a_s2, const float* __restrict__ a_d2,
            const float* __restrict__ b2, float* __restrict__ out) {
    const int n = blockIdx.x * 16 + (threadIdx.x >> 4);
    if (n >= kN) return;
    const int l = threadIdx.x & 15;
    const float as = a_s2[0], ad = a_d2[0];
    const int beg = rowptr[n], end = rowptr[n + 1];
    const float hd = h2[n] * ad;
    float sw = 0.f, swh = 0.f;
    for (int p = beg + l; p < end; p += 16) {
        float hs = h2[es[p]];
        float w = expf(lrelu(hs * as + hd));
        sw += w;
        swh += w * hs;
    }
#pragma unroll
    for (int off = 8; off >= 1; off >>= 1) {
        sw  += __shfl_xor(sw, off, 64);
        swh += __shfl_xor(swh, off, 64);
    }
    if (l == 0) out[n] = swh / sw + b2[0];
}

extern "C" void kernel_launch(void* const* d_in, const int* in_sizes, int n_in,
                              void* d_out, int out_size, void* d_ws, size_t ws_size,
                              hipStream_t stream) {
    const float* x      = (const float*)d_in[0];
    const int*   ei     = (const int*)d_in[1];
    const float* W1     = (const float*)d_in[3];
    const float* a_src1 = (const float*)d_in[4];
    const float* a_dst1 = (const float*)d_in[5];
    const float* b1     = (const float*)d_in[6];
    const float* W2     = (const float*)d_in[7];
    const float* a_src2 = (const float*)d_in[8];
    const float* a_dst2 = (const float*)d_in[9];
    const float* b2     = (const float*)d_in[10];
    float* out = (float*)d_out;

    const int E  = in_sizes[1] / 2;      // 800000
    const int E2 = E + kN;               // 850000

    // workspace layout (float offsets)
    float*  ws    = (float*)d_ws;
    float*  asrc  = ws;                          //   200,000 f
    float*  adst  = ws + 200000;                 //   200,000 f
    float*  h2    = ws + 400000;                 //    50,000 f
    __half* h1h   = (__half*)(ws + 450000);      // 6,400,000 h = 3,200,000 f
    float*  wgt   = ws + 3650000;                // 3,400,000 f (per-edge weights x4)
    int*    ibase = (int*)(ws + 7050000);
    int*    es     = ibase;                      //   850,000 i
    int*    deg    = ibase + 850000;             //    50,000 i
    int*    cnt    = ibase + 900000;             //    50,000 i
    int*    loc    = ibase + 950000;             //    50,000 i
    int*    rowptr = ibase + 1000000;            //    50,001 i
    int*    bsum   = ibase + 1050016;            //       256 i

    k_init<<<(100000 + 255) / 256, 256, 0, stream>>>(deg, 100000);  // deg+cnt contiguous

    k_hist<<<(E2 + 255) / 256, 256, 0, stream>>>(ei, E, deg);
    k_scan_a<<<kScanNB, kScanB, 0, stream>>>(deg, loc, bsum);
    k_scan_b<<<1, 256, 0, stream>>>(bsum);
    k_scan_c<<<kScanNB, kScanB, 0, stream>>>(loc, bsum, rowptr, E2);

    {
        const int nPass = (kN + 31) / 32;        // 1563
        k_gemm1<<<512, 256, 0, stream>>>(x, W1, a_src1, a_dst1, h1h, asrc, adst, nPass, 512);
    }

    k_scatter<<<(E2 + 255) / 256, 256, 0, stream>>>(ei, E, asrc, adst, rowptr, cnt, es, wgt);

    k_agg1<<<(kN + 3) / 4, 256, 0, stream>>>(rowptr, es, wgt, h1h, b1, W2, h2);

    k_agg2<<<(kN + 15) / 16, 256, 0, stream>>>(rowptr, es, h2, a_src2, a_dst2, b2, out);
}

// Round 12
// 198.448 us; speedup vs baseline: 1.2591x; 1.0215x over previous
//
#include <hip/hip_runtime.h>
#include <hip/hip_fp16.h>
#include <math.h>
#include <stdint.h>

static constexpr int kN     = 50000;
static constexpr int kFIn   = 128;
static constexpr int kHeads = 4;
static constexpr int kScanB = 256;
static constexpr int kScanNB = (kN + kScanB - 1) / kScanB;   // 196

__device__ __forceinline__ float lrelu(float x) { return x > 0.f ? x : 0.2f * x; }

// value-level (address-free) unpack/pack of 2 halves in a float's bits
__device__ __forceinline__ float2 h2pair(float fbits) {
    const uint32_t u = __float_as_uint(fbits);
    const __half2 h = __builtin_bit_cast(__half2, u);
    return __half22float2(h);
}
__device__ __forceinline__ float pack2h(float a, float b) {
    const __half2 h = __floats2half2_rn(a, b);
    return __uint_as_float(__builtin_bit_cast(uint32_t, h));
}

// ---- init: zero deg + cnt (contiguous) ----
__global__ void k_init(int* __restrict__ p, int n) {
    int i = blockIdx.x * blockDim.x + threadIdx.x;
    if (i < n) p[i] = 0;
}

// ---- layer 1 node transform: h1 = x@W1 (fp16 out), attention logits fused.
// W1 in LDS as FP16 (32 KB), granule-rotated: chunk c (8 halves = 16B) of channel
// j at granule j*16 + ((c+j)&15); slot = (c+j)&7 -> conflict-free (same math
// verified at 0 conflicts in R8-R11). x tile (32 nodes, 16 KB fp32) staged per
// pass coalesced, read as LDS broadcast (R10 win). 48 KB total -> 3 blocks/CU
// (12 waves/CU, +50% vs R11's 2 blocks) to lift VALUBusy from 49%.
// Spill guards (R5/R7 lesson): NO launch_bounds min-wave cap, unroll limited to 4,
// value-level unpack only. If VGPR reads ~64 + GB-scale FETCH: spill recurred.
__global__ __launch_bounds__(256)
void k_gemm1(const float* __restrict__ x, const float* __restrict__ W1,
             const float* __restrict__ a_src1, const float* __restrict__ a_dst1,
             __half* __restrict__ h1h, float* __restrict__ asrc, float* __restrict__ adst,
             int nPass, int grid) {
    __shared__ __align__(16) float whf[128 * 16 * 4];  // 8192 floats = 32 KB (fp16 W1, packed)
    __shared__ __align__(16) float xs[32 * 128];       // 16 KB (x tile, fp32)
    const int t = threadIdx.x;
    const int j = t & 63;                            // lane
    const int g = t >> 6;                            // wave 0..3
    // stage W1 -> fp16 granules: idx -> (c = idx>>7 in 0..15, col = idx&127)
    for (int idx = t; idx < 2048; idx += 256) {
        const int c = idx >> 7, col = idx & 127;
        float4 st;
        st.x = pack2h(W1[(8 * c + 0) * 128 + col], W1[(8 * c + 1) * 128 + col]);
        st.y = pack2h(W1[(8 * c + 2) * 128 + col], W1[(8 * c + 3) * 128 + col]);
        st.z = pack2h(W1[(8 * c + 4) * 128 + col], W1[(8 * c + 5) * 128 + col]);
        st.w = pack2h(W1[(8 * c + 6) * 128 + col], W1[(8 * c + 7) * 128 + col]);
        const int gran = col * 16 + ((c + col) & 15);
        *reinterpret_cast<float4*>(&whf[gran * 4]) = st;
    }
    const float as0 = a_src1[j], as1 = a_src1[j + 64];
    const float ad0 = a_dst1[j], ad1 = a_dst1[j + 64];
    __syncthreads();

    for (int pass = blockIdx.x; pass < nPass; pass += grid) {
        const int nodeBase = pass * 32;
        for (int q = t; q < 1024; q += 256) {
            const int nn = q >> 5;
            const int ck = q & 31;
            int n = nodeBase + nn; if (n >= kN) n = kN - 1;
            *reinterpret_cast<float4*>(&xs[q * 4]) =
                *reinterpret_cast<const float4*>(&x[(size_t)n * 128 + ck * 4]);
        }
        __syncthreads();

        const int base = g * 8;
        float acc[2][8] = {};
#pragma unroll 4
        for (int c = 0; c < 16; ++c) {               // 8 k-values per iter
            const int rot = (c + j) & 15;            // ch j+64: same rot (64&15==0)
            const float4 w0raw = *(const float4*)&whf[(j * 16 + rot) * 4];
            const float4 w1raw = *(const float4*)&whf[((j + 64) * 16 + rot) * 4];
            const float2 a01 = h2pair(w0raw.x), a23 = h2pair(w0raw.y);
            const float2 a45 = h2pair(w0raw.z), a67 = h2pair(w0raw.w);
            const float2 b01 = h2pair(w1raw.x), b23 = h2pair(w1raw.y);
            const float2 b45 = h2pair(w1raw.z), b67 = h2pair(w1raw.w);
#pragma unroll
            for (int nn = 0; nn < 8; ++nn) {
                const float4 xa = *(const float4*)&xs[(base + nn) * 128 + 8 * c];      // broadcast
                const float4 xb = *(const float4*)&xs[(base + nn) * 128 + 8 * c + 4];  // broadcast
                acc[0][nn] += a01.x * xa.x + a01.y * xa.y + a23.x * xa.z + a23.y * xa.w
                            + a45.x * xb.x + a45.y * xb.y + a67.x * xb.z + a67.y * xb.w;
                acc[1][nn] += b01.x * xa.x + b01.y * xa.y + b23.x * xa.z + b23.y * xa.w
                            + b45.x * xb.x + b45.y * xb.y + b67.x * xb.z + b67.y * xb.w;
            }
        }
#pragma unroll
        for (int nn = 0; nn < 8; ++nn) {
            const int n = nodeBase + base + nn;
            const bool valid = (n < kN);
            if (valid) {
                h1h[(size_t)n * 128 + j]      = __float2half(acc[0][nn]);
                h1h[(size_t)n * 128 + 64 + j] = __float2half(acc[1][nn]);
            }
            float ps0 = acc[0][nn] * as0, ps1 = acc[1][nn] * as1;
            float pd0 = acc[0][nn] * ad0, pd1 = acc[1][nn] * ad1;
#pragma unroll
            for (int off = 16; off >= 1; off >>= 1) {
                ps0 += __shfl_xor(ps0, off, 64);
                ps1 += __shfl_xor(ps1, off, 64);
                pd0 += __shfl_xor(pd0, off, 64);
                pd1 += __shfl_xor(pd1, off, 64);
            }
            if (valid && ((j & 31) == 0)) {
                const int h01 = j >> 5;
                asrc[n * 4 + h01]     = ps0;
                asrc[n * 4 + 2 + h01] = ps1;
                adst[n * 4 + h01]     = pd0;
                adst[n * 4 + 2 + h01] = pd1;
            }
        }
        __syncthreads();
    }
}

// ---- CSR build ----
__global__ void k_hist(const int* __restrict__ ei, int E, int* __restrict__ deg) {
    int i = blockIdx.x * blockDim.x + threadIdx.x;
    int total = E + kN;
    if (i >= total) return;
    int d = (i < E) ? ei[E + i] : (i - E);
    atomicAdd(&deg[d], 1);
}

__global__ void k_scan_a(const int* __restrict__ deg, int* __restrict__ loc, int* __restrict__ bsum) {
    __shared__ int tmp[kScanB];
    int t = threadIdx.x;
    int i = blockIdx.x * kScanB + t;
    int v = (i < kN) ? deg[i] : 0;
    tmp[t] = v;
    __syncthreads();
    for (int off = 1; off < kScanB; off <<= 1) {
        int add = (t >= off) ? tmp[t - off] : 0;
        __syncthreads();
        tmp[t] += add;
        __syncthreads();
    }
    if (i < kN) loc[i] = tmp[t] - v;     // exclusive within block
    if (t == kScanB - 1) bsum[blockIdx.x] = tmp[t];
}

__global__ void k_scan_b(int* __restrict__ bsum) {
    __shared__ int tmp[256];
    int t = threadIdx.x;
    int v = (t < kScanNB) ? bsum[t] : 0;
    tmp[t] = v;
    __syncthreads();
    for (int off = 1; off < 256; off <<= 1) {
        int add = (t >= off) ? tmp[t - off] : 0;
        __syncthreads();
        tmp[t] += add;
        __syncthreads();
    }
    if (t < kScanNB) bsum[t] = tmp[t] - v;   // exclusive
}

__global__ void k_scan_c(const int* __restrict__ loc, const int* __restrict__ bsum,
                         int* __restrict__ rowptr, int E2) {
    int i = blockIdx.x * kScanB + threadIdx.x;
    if (i < kN) rowptr[i] = loc[i] + bsum[blockIdx.x];
    if (i == 0) rowptr[kN] = E2;
}

// ---- scatter: bucket edges by dst AND precompute the 4 per-edge softmax weights ----
__global__ void k_scatter(const int* __restrict__ ei, int E,
                          const float* __restrict__ asrc, const float* __restrict__ adst,
                          const int* __restrict__ rowptr, int* __restrict__ cnt,
                          int* __restrict__ es, float* __restrict__ wgt) {
    int i = blockIdx.x * blockDim.x + threadIdx.x;
    int total = E + kN;
    if (i >= total) return;
    int s, d;
    if (i < E) { s = ei[i]; d = ei[E + i]; } else { s = d = i - E; }
    int pos = rowptr[d] + atomicAdd(&cnt[d], 1);
    es[pos] = s;
    float4 w4;
    w4.x = expf(lrelu(asrc[s * 4 + 0] + adst[d * 4 + 0]));
    w4.y = expf(lrelu(asrc[s * 4 + 1] + adst[d * 4 + 1]));
    w4.z = expf(lrelu(asrc[s * 4 + 2] + adst[d * 4 + 2]));
    w4.w = expf(lrelu(asrc[s * 4 + 3] + adst[d * 4 + 3]));
    *reinterpret_cast<float4*>(&wgt[pos * 4]) = w4;
}

// ---- layer 1 aggregation: pure gather+FMA (weights preloaded), 4-unrolled ----
__global__ __launch_bounds__(256)
void k_agg1(const int* __restrict__ rowptr, const int* __restrict__ es,
            const float* __restrict__ wgt,
            const __half* __restrict__ h1h, const float* __restrict__ b1,
            const float* __restrict__ W2, float* __restrict__ h2) {
    const int n = blockIdx.x * 4 + (threadIdx.x >> 6);
    if (n >= kN) return;
    const int j  = threadIdx.x & 63;     // lane: channels 2j, 2j+1
    const int hh = j >> 4;               // head of both channels
    const int beg = rowptr[n], end = rowptr[n + 1];
    float ax0 = 0.f, ay0 = 0.f, dn0 = 0.f;
    float ax1 = 0.f, ay1 = 0.f, dn1 = 0.f;
    int p = beg;
    for (; p + 4 <= end; p += 4) {
        const int s0 = es[p],     s1 = es[p + 1];
        const int s2 = es[p + 2], s3 = es[p + 3];
        const float w0 = wgt[(p + 0) * 4 + hh];
        const float w1 = wgt[(p + 1) * 4 + hh];
        const float w2 = wgt[(p + 2) * 4 + hh];
        const float w3 = wgt[(p + 3) * 4 + hh];
        const float2 f0 = __half22float2(*(const __half2*)&h1h[s0 * 128 + 2 * j]);
        const float2 f1 = __half22float2(*(const __half2*)&h1h[s1 * 128 + 2 * j]);
        const float2 f2 = __half22float2(*(const __half2*)&h1h[s2 * 128 + 2 * j]);
        const float2 f3 = __half22float2(*(const __half2*)&h1h[s3 * 128 + 2 * j]);
        ax0 += w0 * f0.x; ay0 += w0 * f0.y; dn0 += w0;
        ax1 += w1 * f1.x; ay1 += w1 * f1.y; dn1 += w1;
        ax0 += w2 * f2.x; ay0 += w2 * f2.y; dn0 += w2;
        ax1 += w3 * f3.x; ay1 += w3 * f3.y; dn1 += w3;
    }
    for (; p < end; ++p) {
        const int s0 = es[p];
        const float w0 = wgt[p * 4 + hh];
        const float2 f0 = __half22float2(*(const __half2*)&h1h[s0 * 128 + 2 * j]);
        ax0 += w0 * f0.x; ay0 += w0 * f0.y; dn0 += w0;
    }
    const float den = dn0 + dn1;
    float vx = (ax0 + ax1) / den;
    float vy = (ay0 + ay1) / den;
    vx += __shfl_xor(vx, 32, 64); vy += __shfl_xor(vy, 32, 64);
    vx += __shfl_xor(vx, 16, 64); vy += __shfl_xor(vy, 16, 64);
    const int m = j & 15;
    float u0 = 0.25f * vx + b1[2 * m];
    float u1 = 0.25f * vy + b1[2 * m + 1];
    u0 = u0 > 0.f ? u0 : expf(u0) - 1.f;
    u1 = u1 > 0.f ? u1 : expf(u1) - 1.f;
    float tsum = u0 * W2[2 * m] + u1 * W2[2 * m + 1];
    tsum += __shfl_xor(tsum, 8, 64);
    tsum += __shfl_xor(tsum, 4, 64);
    tsum += __shfl_xor(tsum, 2, 64);
    tsum += __shfl_xor(tsum, 1, 64);
    if (j == 0) h2[n] = tsum;
}

// ---- layer 2: 16 lanes per node, gather h2 (L2-resident), fused bias -> out ----
__global__ __launch_bounds__(256)
void k_agg2(const int* __restrict__ rowptr, const int* __restrict__ es,
            const float* __restrict__ h2,
            const float* __restrict__ a_s2, const float* __restrict__ a_d2,
            const float* __restrict__ b2, float* __restrict__ out) {
    const int n = blockIdx.x * 16 + (threadIdx.x >> 4);
    if (n >= kN) return;
    const int l = threadIdx.x & 15;
    const float as = a_s2[0], ad = a_d2[0];
    const int beg = rowptr[n], end = rowptr[n + 1];
    const float hd = h2[n] * ad;
    float sw = 0.f, swh = 0.f;
    for (int p = beg + l; p < end; p += 16) {
        float hs = h2[es[p]];
        float w = expf(lrelu(hs * as + hd));
        sw += w;
        swh += w * hs;
    }
#pragma unroll
    for (int off = 8; off >= 1; off >>= 1) {
        sw  += __shfl_xor(sw, off, 64);
        swh += __shfl_xor(swh, off, 64);
    }
    if (l == 0) out[n] = swh / sw + b2[0];
}

extern "C" void kernel_launch(void* const* d_in, const int* in_sizes, int n_in,
                              void* d_out, int out_size, void* d_ws, size_t ws_size,
                              hipStream_t stream) {
    const float* x      = (const float*)d_in[0];
    const int*   ei     = (const int*)d_in[1];
    const float* W1     = (const float*)d_in[3];
    const float* a_src1 = (const float*)d_in[4];
    const float* a_dst1 = (const float*)d_in[5];
    const float* b1     = (const float*)d_in[6];
    const float* W2     = (const float*)d_in[7];
    const float* a_src2 = (const float*)d_in[8];
    const float* a_dst2 = (const float*)d_in[9];
    const float* b2     = (const float*)d_in[10];
    float* out = (float*)d_out;

    const int E  = in_sizes[1] / 2;      // 800000
    const int E2 = E + kN;               // 850000

    // workspace layout (float offsets)
    float*  ws    = (float*)d_ws;
    float*  asrc  = ws;                          //   200,000 f
    float*  adst  = ws + 200000;                 //   200,000 f
    float*  h2    = ws + 400000;                 //    50,000 f
    __half* h1h   = (__half*)(ws + 450000);      // 6,400,000 h = 3,200,000 f
    float*  wgt   = ws + 3650000;                // 3,400,000 f (per-edge weights x4)
    int*    ibase = (int*)(ws + 7050000);
    int*    es     = ibase;                      //   850,000 i
    int*    deg    = ibase + 850000;             //    50,000 i
    int*    cnt    = ibase + 900000;             //    50,000 i
    int*    loc    = ibase + 950000;             //    50,000 i
    int*    rowptr = ibase + 1000000;            //    50,001 i
    int*    bsum   = ibase + 1050016;            //       256 i

    k_init<<<(100000 + 255) / 256, 256, 0, stream>>>(deg, 100000);  // deg+cnt contiguous

    k_hist<<<(E2 + 255) / 256, 256, 0, stream>>>(ei, E, deg);
    k_scan_a<<<kScanNB, kScanB, 0, stream>>>(deg, loc, bsum);
    k_scan_b<<<1, 256, 0, stream>>>(bsum);
    k_scan_c<<<kScanNB, kScanB, 0, stream>>>(loc, bsum, rowptr, E2);

    {
        const int nPass = (kN + 31) / 32;        // 1563
        k_gemm1<<<512, 256, 0, stream>>>(x, W1, a_src1, a_dst1, h1h, asrc, adst, nPass, 512);
    }

    k_scatter<<<(E2 + 255) / 256, 256, 0, stream>>>(ei, E, asrc, adst, rowptr, cnt, es, wgt);

    k_agg1<<<(kN + 3) / 4, 256, 0, stream>>>(rowptr, es, wgt, h1h, b1, W2, h2);

    k_agg2<<<(kN + 15) / 16, 256, 0, stream>>>(rowptr, es, h2, a_src2, a_dst2, b2, out);
}